// Round 1
// baseline (31708.749 us; speedup 1.0000x reference)
//
#include <hip/hip_runtime.h>

// GCN propagation: h <- A_norm h, 12 times.
// deg[i] = 1 + #edges with dst==i ; coef(e) = rsqrt(deg[src])*rsqrt(deg[dst])
// self coef = 1/deg. Isolated nodes (in no edge) are zeroed up front.

__global__ void k_init(float* __restrict__ deg, int* __restrict__ nonisol, int n) {
    int i = blockIdx.x * blockDim.x + threadIdx.x;
    if (i < n) { deg[i] = 1.0f; nonisol[i] = 0; }
}

__global__ void k_edge_deg(const int* __restrict__ src, const int* __restrict__ dst,
                           float* __restrict__ deg, int* __restrict__ nonisol, int e) {
    int i = blockIdx.x * blockDim.x + threadIdx.x;
    if (i < e) {
        int s = src[i], d = dst[i];
        nonisol[s] = 1;           // benign race: everyone writes 1
        nonisol[d] = 1;
        atomicAdd(&deg[d], 1.0f); // exact for counts << 2^24
    }
}

__global__ void k_init_h(const float4* __restrict__ x, const float* __restrict__ deg,
                         float* __restrict__ inv_sqrt, const int* __restrict__ nonisol,
                         float4* __restrict__ h, int n) {
    int i = blockIdx.x * blockDim.x + threadIdx.x;
    if (i < n) {
        float is = rsqrtf(deg[i]);
        inv_sqrt[i] = is;
        bool ni = nonisol[i] != 0;
        float4 z = make_float4(0.f, 0.f, 0.f, 0.f);
#pragma unroll
        for (int q = 0; q < 4; ++q)
            h[(size_t)i * 4 + q] = ni ? x[(size_t)i * 4 + q] : z;
    }
}

// hn[i][:] = h[i][:] * (1/deg[i])  -- also fully initializes hn
__global__ void k_self(const float4* __restrict__ h, const float* __restrict__ inv_sqrt,
                       float4* __restrict__ hn, int n4) {
    int i = blockIdx.x * blockDim.x + threadIdx.x;
    if (i < n4) {
        float is = inv_sqrt[i >> 2];
        float c = is * is;
        float4 v = h[i];
        v.x *= c; v.y *= c; v.z *= c; v.w *= c;
        hn[i] = v;
    }
}

// one thread per edge: hn[dst] += h[src] * coef  (16 scalar f32 atomics)
__global__ void k_edge(const int* __restrict__ src, const int* __restrict__ dst,
                       const float* __restrict__ inv_sqrt,
                       const float4* __restrict__ h, float* __restrict__ hn, int e) {
    int i = blockIdx.x * blockDim.x + threadIdx.x;
    if (i < e) {
        int s = src[i], d = dst[i];
        float c = inv_sqrt[s] * inv_sqrt[d];
        float* out = hn + (size_t)d * 16;
#pragma unroll
        for (int q = 0; q < 4; ++q) {
            float4 v = h[(size_t)s * 4 + q];
            atomicAdd(out + q * 4 + 0, v.x * c);
            atomicAdd(out + q * 4 + 1, v.y * c);
            atomicAdd(out + q * 4 + 2, v.z * c);
            atomicAdd(out + q * 4 + 3, v.w * c);
        }
    }
}

extern "C" void kernel_launch(void* const* d_in, const int* in_sizes, int n_in,
                              void* d_out, int out_size, void* d_ws, size_t ws_size,
                              hipStream_t stream) {
    const float* x  = (const float*)d_in[0];
    const int*   ei = (const int*)d_in[1];
    const int n = in_sizes[0] / 16;   // 100000
    const int e = in_sizes[1] / 2;    // 3200000
    const int* src = ei;
    const int* dst = ei + e;

    // workspace partition (256B aligned)
    char* ws = (char*)d_ws;
    auto take = [&](size_t bytes) {
        char* p = ws;
        ws += (bytes + 255) & ~(size_t)255;
        return p;
    };
    float* deg     = (float*)take((size_t)n * sizeof(float));
    float* invs    = (float*)take((size_t)n * sizeof(float));
    int*   nonisol = (int*)take((size_t)n * sizeof(int));
    float* hws     = (float*)take((size_t)n * 16 * sizeof(float));
    float* hout    = (float*)d_out;

    const int B = 256;
    const int gn  = (n + B - 1) / B;
    const int ge  = (e + B - 1) / B;
    const int gn4 = (n * 4 + B - 1) / B;

    k_init<<<gn, B, 0, stream>>>(deg, nonisol, n);
    k_edge_deg<<<ge, B, 0, stream>>>(src, dst, deg, nonisol, e);
    k_init_h<<<gn, B, 0, stream>>>((const float4*)x, deg, invs, nonisol, (float4*)hout, n);

    float* cur = hout;  // 12 layers (even) -> final result lands back in d_out
    float* nxt = hws;
    for (int l = 0; l < 12; ++l) {
        k_self<<<gn4, B, 0, stream>>>((const float4*)cur, invs, (float4*)nxt, n * 4);
        k_edge<<<ge, B, 0, stream>>>(src, dst, invs, (const float4*)cur, nxt, e);
        float* t = cur; cur = nxt; nxt = t;
    }
}

// Round 2
// 1164.174 us; speedup vs baseline: 27.2371x; 27.2371x over previous
//
#include <hip/hip_runtime.h>

// h <- A_norm h, 12 times, via dst-bucketed CSR built on device each call.
// deg[i] = 1 + indeg(i); edge coef = invs[src]*invs[dst]; self coef = invs^2.
// Isolated nodes (in no edge at all) zeroed once up front.

__global__ void k_init(int* __restrict__ cnt, int* __restrict__ nonisol, int n) {
    int i = blockIdx.x * blockDim.x + threadIdx.x;
    if (i < n) { cnt[i] = 0; nonisol[i] = 0; }
}

__global__ void k_count(const int* __restrict__ src, const int* __restrict__ dst,
                        int* __restrict__ cnt, int* __restrict__ nonisol, int e) {
    int i = blockIdx.x * blockDim.x + threadIdx.x;
    if (i < e) {
        int s = src[i], d = dst[i];
        nonisol[s] = 1;            // benign race
        nonisol[d] = 1;
        atomicAdd(&cnt[d], 1);
    }
}

// invs = rsqrt(cnt+1); h0 = nonisol ? x : 0
__global__ void k_init_h(const float4* __restrict__ x, const int* __restrict__ cnt,
                         float* __restrict__ invs, const int* __restrict__ nonisol,
                         float4* __restrict__ h, int n) {
    int i = blockIdx.x * blockDim.x + threadIdx.x;
    if (i < n) {
        invs[i] = rsqrtf((float)(cnt[i] + 1));
        bool ni = nonisol[i] != 0;
        float4 z = make_float4(0.f, 0.f, 0.f, 0.f);
#pragma unroll
        for (int q = 0; q < 4; ++q)
            h[(size_t)i * 4 + q] = ni ? x[(size_t)i * 4 + q] : z;
    }
}

// ---- 3-pass exclusive scan of cnt[0..n) -> rowptr, cursor ----
__global__ void k_scan1(const int* __restrict__ cnt, int* __restrict__ partial, int n) {
    __shared__ int sd[256];
    int i = blockIdx.x * 256 + threadIdx.x;
    sd[threadIdx.x] = (i < n) ? cnt[i] : 0;
    __syncthreads();
    for (int s = 128; s > 0; s >>= 1) {
        if (threadIdx.x < s) sd[threadIdx.x] += sd[threadIdx.x + s];
        __syncthreads();
    }
    if (threadIdx.x == 0) partial[blockIdx.x] = sd[0];
}

__global__ void k_scan2(int* __restrict__ partial, int nb) {
    __shared__ int sd[512];
    int t = threadIdx.x;
    int v = (t < nb) ? partial[t] : 0;
    sd[t] = v;
    __syncthreads();
    for (int off = 1; off < 512; off <<= 1) {
        int add = (t >= off) ? sd[t - off] : 0;
        __syncthreads();
        sd[t] += add;
        __syncthreads();
    }
    if (t < nb) partial[t] = sd[t] - v;   // exclusive
}

__global__ void k_scan3(const int* __restrict__ cnt, const int* __restrict__ partial,
                        int* __restrict__ rowptr, int* __restrict__ cursor, int n, int e) {
    __shared__ int sd[256];
    int i = blockIdx.x * 256 + threadIdx.x;
    int v = (i < n) ? cnt[i] : 0;
    sd[threadIdx.x] = v;
    __syncthreads();
    for (int off = 1; off < 256; off <<= 1) {
        int add = (threadIdx.x >= off) ? sd[threadIdx.x - off] : 0;
        __syncthreads();
        sd[threadIdx.x] += add;
        __syncthreads();
    }
    int ex = sd[threadIdx.x] - v + partial[blockIdx.x];
    if (i < n) { rowptr[i] = ex; cursor[i] = ex; }
    if (i == n - 1) rowptr[n] = e;
}

__global__ void k_scatter(const int* __restrict__ src, const int* __restrict__ dst,
                          int* __restrict__ cursor, int* __restrict__ adj, int e) {
    int i = blockIdx.x * blockDim.x + threadIdx.x;
    if (i < e) {
        int d = dst[i];
        int pos = atomicAdd(&cursor[d], 1);
        adj[pos] = src[i];
    }
}

// 4 threads per node; lane q owns float4 quadrant q of the 16 features.
__global__ void k_layer(const int* __restrict__ rowptr, const int* __restrict__ adj,
                        const float* __restrict__ invs,
                        const float4* __restrict__ h, float4* __restrict__ hn, int n) {
    int t = blockIdx.x * blockDim.x + threadIdx.x;
    int node = t >> 2, q = t & 3;
    if (node >= n) return;
    float is = invs[node];
    float c0 = is * is;
    float4 acc = h[(size_t)node * 4 + q];
    acc.x *= c0; acc.y *= c0; acc.z *= c0; acc.w *= c0;
    int beg = rowptr[node], end = rowptr[node + 1];
    for (int k = beg; k < end; ++k) {
        int s = adj[k];
        float c = invs[s] * is;
        float4 v = h[(size_t)s * 4 + q];
        acc.x += v.x * c; acc.y += v.y * c; acc.z += v.z * c; acc.w += v.w * c;
    }
    hn[(size_t)node * 4 + q] = acc;
}

extern "C" void kernel_launch(void* const* d_in, const int* in_sizes, int n_in,
                              void* d_out, int out_size, void* d_ws, size_t ws_size,
                              hipStream_t stream) {
    const float* x  = (const float*)d_in[0];
    const int*   ei = (const int*)d_in[1];
    const int n = in_sizes[0] / 16;   // 100000
    const int e = in_sizes[1] / 2;    // 3200000
    const int* src = ei;
    const int* dst = ei + e;

    char* ws = (char*)d_ws;
    auto take = [&](size_t bytes) {
        char* p = ws;
        ws += (bytes + 255) & ~(size_t)255;
        return p;
    };
    int*   cnt     = (int*)take((size_t)n * sizeof(int));
    int*   nonisol = (int*)take((size_t)n * sizeof(int));
    int*   rowptr  = (int*)take((size_t)(n + 1) * sizeof(int));
    int*   cursor  = (int*)take((size_t)n * sizeof(int));
    float* invs    = (float*)take((size_t)n * sizeof(float));
    int*   partial = (int*)take(512 * sizeof(int));
    int*   adj     = (int*)take((size_t)e * sizeof(int));
    float* hws     = (float*)take((size_t)n * 16 * sizeof(float));
    float* hout    = (float*)d_out;

    const int B = 256;
    const int gn  = (n + B - 1) / B;       // 391
    const int ge  = (e + B - 1) / B;
    const int gn4 = (n * 4 + B - 1) / B;   // 1563

    k_init<<<gn, B, 0, stream>>>(cnt, nonisol, n);
    k_count<<<ge, B, 0, stream>>>(src, dst, cnt, nonisol, e);
    k_init_h<<<gn, B, 0, stream>>>((const float4*)x, cnt, invs, nonisol, (float4*)hout, n);
    k_scan1<<<gn, B, 0, stream>>>(cnt, partial, n);
    k_scan2<<<1, 512, 0, stream>>>(partial, gn);
    k_scan3<<<gn, B, 0, stream>>>(cnt, partial, rowptr, cursor, n, e);
    k_scatter<<<ge, B, 0, stream>>>(src, dst, cursor, adj, e);

    float* cur = hout;   // 12 layers (even) -> result ends in d_out
    float* nxt = hws;
    for (int l = 0; l < 12; ++l) {
        k_layer<<<gn4, B, 0, stream>>>(rowptr, adj, invs, (const float4*)cur, (float4*)nxt, n);
        float* t = cur; cur = nxt; nxt = t;
    }
}